// Round 11
// baseline (600.559 us; speedup 1.0000x reference)
//
#include <hip/hip_runtime.h>
#include <stdint.h>

#define NROWS 8192
#define DDIM  128
#define NBI   64                         // row blocks (128 rows each)
#define NBJ   32                         // col blocks (256 cols each)
#define LOG2E_X100 144.26950408889634f   // 100 / ln(2)
#define LN2F       0.6931471805599453f

typedef __bf16 bf16x8 __attribute__((ext_vector_type(8)));
typedef float  f32x4  __attribute__((ext_vector_type(4)));
typedef unsigned short u16x8 __attribute__((ext_vector_type(8)));

// Fragment-major (F) layout: for strip g (16 rows), k-chunk kc (32 cols):
//   1 KB block at byte offset (g*4+kc)*1024; lane L=(quad*16+c) piece at L*16,
//   holding row (g*16+c), bytes [(kc*4+quad)*16 .. +16).
// DMA (global->LDS), ds_read, and A-frag loads all run at linear lane*16.

__device__ __forceinline__ unsigned short f2bf_rne(float f) {
    union { float f; uint32_t u; } v; v.f = f;
    uint32_t r = (v.u + 0x7FFFu + ((v.u >> 16) & 1u)) >> 16;
    return (unsigned short)r;
}

__device__ __forceinline__ void async16(const unsigned short* g, unsigned char* l) {
    __builtin_amdgcn_global_load_lds(
        (const __attribute__((address_space(1))) unsigned int*)g,
        (__attribute__((address_space(3))) unsigned int*)l, 16, 0, 0);
}

// Kernel 1: fp32 -> bf16 into FRAGMENT-MAJOR layout; ts pre-scaled by
// 100*log2(e) (base-2 softmax space). Zeroes acc + ctrl[0..32].
__global__ void convert_kernel(const float* __restrict__ ts, const float* __restrict__ nt,
                               unsigned short* __restrict__ ts_bf,
                               unsigned short* __restrict__ nt_bf,
                               float* __restrict__ acc, int* __restrict__ ctrl) {
    const int nchunk = (NROWS * DDIM) / 8;
    int tid = blockIdx.x * blockDim.x + threadIdx.x;
    bool isNT = tid >= nchunk;
    int i = isNT ? (tid - nchunk) : tid;
    const float4* src = (const float4*)(isNT ? nt : ts) + i * 2;
    float4 v0 = src[0], v1 = src[1];
    float sc = isNT ? 1.0f : LOG2E_X100;
    u16x8 o;
    o[0] = f2bf_rne(v0.x * sc); o[1] = f2bf_rne(v0.y * sc);
    o[2] = f2bf_rne(v0.z * sc); o[3] = f2bf_rne(v0.w * sc);
    o[4] = f2bf_rne(v1.x * sc); o[5] = f2bf_rne(v1.y * sc);
    o[6] = f2bf_rne(v1.z * sc); o[7] = f2bf_rne(v1.w * sc);
    int row = i >> 4, chunk = i & 15;
    int g = row >> 4, c = row & 15;
    int kc = chunk >> 2, quad = chunk & 3;
    int off16 = (g * 4 + kc) * 64 + quad * 16 + c;
    ((u16x8*)(isNT ? nt_bf : ts_bf))[off16] = o;
    if (tid < 33) ctrl[tid] = 0;
    if (tid == 33) *acc = 0.0f;
}

// DMA one 64-col stage (16 KB contiguous in F layout), split across 8 waves.
__device__ __forceinline__ void dma_stage(const unsigned short* g, unsigned char* l,
                                          int lane, int wv) {
#pragma unroll
    for (int k = 0; k < 2; ++k) {
        int u = wv * 2 + k;
        async16(g + u * 512 + lane * 8, l + u * 1024);
    }
}

// Kernel 2: FUSED tile kernel v2. Block (I,J) computes the 128x256 tile once;
// slots processed in PAIRS (half the accumulator live-set => no spills):
// row-stats online (2-batch), col-stats per slot (butterfly-max, common-max
// exps, butterfly-add). Merge fused at end via per-group counters.
// grid = (NBI, NBJ), 8 waves/block, 3 blocks/CU (LDS 48KB).
__global__ __launch_bounds__(512, 3) void tile_kernel(
        const unsigned short* __restrict__ ts_bf,
        const unsigned short* __restrict__ nt_bf,
        float* __restrict__ pm, float* __restrict__ ps,
        float* __restrict__ cm, float* __restrict__ cs,
        float* __restrict__ diag, float* __restrict__ acc,
        int* __restrict__ ctrl, float* __restrict__ out) {
    __shared__ unsigned char smem[2 * 16384];
    __shared__ float2 colp[8][256];            // per-wave col partials (M,S)
    __shared__ float wsum[8];
    __shared__ int mflag;

    const int lane = threadIdx.x & 63;
    const int wv   = threadIdx.x >> 6;
    const int c    = lane & 15;
    const int quad = lane >> 4;
    const int I    = blockIdx.x;               // row block (128 rows)
    const int J    = blockIdx.y;               // col block (256 cols)
    const int g    = I * 8 + wv;               // this wave's strip
    const int rows0 = g * 16;

    // A fragments: one strip, lane-linear coalesced (16 VGPRs).
    bf16x8 a[4];
#pragma unroll
    for (int kc = 0; kc < 4; ++kc)
        a[kc] = *(const bf16x8*)(ts_bf + (g * 4 + kc) * 512 + lane * 8);

    float m[4], ss[4], dg[4];
#pragma unroll
    for (int r = 0; r < 4; ++r) { m[r] = -INFINITY; ss[r] = 0.0f; dg[r] = 0.0f; }

    // Diagonal: block (I, I>>1); wave's diag tile -> stage t_d, slot l_d.
    const bool diagB = (J == (I >> 1));
    const int  t_d = 2 * (I & 1) + (wv >> 2);
    const int  l_d = wv & 3;

    const unsigned short* bwalk = nt_bf + J * 16 * 2048;   // strip 16J

    dma_stage(bwalk, smem, lane, wv);
    __syncthreads();

    for (int t = 0; t < 4; ++t) {
        if (t + 1 < 4)
            dma_stage(bwalk + (t + 1) * 8192, smem + ((t + 1) & 1) * 16384, lane, wv);

        const unsigned char* buf = smem + (t & 1) * 16384 + lane * 16;
        const bool pd_ = diagB && (t == t_d);   // wave-uniform

#pragma unroll
        for (int p = 0; p < 2; ++p) {           // slot pair {2p, 2p+1}
            f32x4 av0 = {0.f, 0.f, 0.f, 0.f}, av1 = {0.f, 0.f, 0.f, 0.f};
#pragma unroll
            for (int kc = 0; kc < 4; ++kc) {
                bf16x8 b0 = *(const bf16x8*)(buf + kc * 1024 + (2 * p) * 4096);
                bf16x8 b1 = *(const bf16x8*)(buf + kc * 1024 + (2 * p + 1) * 4096);
                av0 = __builtin_amdgcn_mfma_f32_16x16x32_bf16(a[kc], b0, av0, 0, 0, 0);
                av1 = __builtin_amdgcn_mfma_f32_16x16x32_bf16(a[kc], b1, av1, 0, 0, 0);
            }

            const bool pdp = pd_ && ((l_d >> 1) == p);   // wave-uniform

            // Row phase (2-batch online update).
#pragma unroll
            for (int r = 0; r < 4; ++r) {
                float x0 = av0[r], x1 = av1[r];
                if (pdp) {
                    bool onDiag = (c == quad * 4 + r);
                    float xv = (l_d & 1) ? x1 : x0;
                    if (onDiag) dg[r] += xv;
                    float rep = onDiag ? xv : -1.0e30f;
                    if (l_d & 1) x1 = rep; else x0 = rep;
                }
                float mn = fmaxf(fmaxf(x0, x1), m[r]);   // v_max3
                float e  = __builtin_amdgcn_exp2f(m[r] - mn);
                ss[r] = fmaf(ss[r], e, __builtin_amdgcn_exp2f(x0 - mn)
                                      + __builtin_amdgcn_exp2f(x1 - mn));
                m[r] = mn;
            }

            // Col phase for the two slots of this pair.
#pragma unroll
            for (int q = 0; q < 2; ++q) {
                const int l = 2 * p + q;
                float v0 = q ? av1[0] : av0[0];
                float v1 = q ? av1[1] : av0[1];
                float v2 = q ? av1[2] : av0[2];
                float v3 = q ? av1[3] : av0[3];
                if (pd_ && l == l_d) {          // re-apply mask inline
                    v0 = (c == quad * 4 + 0) ? v0 : -1.0e30f;
                    v1 = (c == quad * 4 + 1) ? v1 : -1.0e30f;
                    v2 = (c == quad * 4 + 2) ? v2 : -1.0e30f;
                    v3 = (c == quad * 4 + 3) ? v3 : -1.0e30f;
                }
                float M = fmaxf(fmaxf(v0, v1), fmaxf(v2, v3));
                M = fmaxf(M, __shfl_xor(M, 16, 64));
                M = fmaxf(M, __shfl_xor(M, 32, 64));
                float S = (__builtin_amdgcn_exp2f(v0 - M) + __builtin_amdgcn_exp2f(v1 - M))
                        + (__builtin_amdgcn_exp2f(v2 - M) + __builtin_amdgcn_exp2f(v3 - M));
                S += __shfl_xor(S, 16, 64);
                S += __shfl_xor(S, 32, 64);
                if (quad == 0) colp[wv][t * 64 + l * 16 + c] = make_float2(M, S);
            }
        }
        __syncthreads();
    }

    // Row epilogue: combine the 16 lanes of each quad; write row partials.
#pragma unroll
    for (int r = 0; r < 4; ++r) {
        float mm = m[r];
#pragma unroll
        for (int off = 1; off < 16; off <<= 1)
            mm = fmaxf(mm, __shfl_xor(mm, off, 64));
        float sv = ss[r] * __builtin_amdgcn_exp2f(m[r] - mm);
        float dd = dg[r];
#pragma unroll
        for (int off = 1; off < 16; off <<= 1) {
            sv += __shfl_xor(sv, off, 64);
            dd += __shfl_xor(dd, off, 64);
        }
        if (c == 0) {
            int row = rows0 + quad * 4 + r;
            pm[row * NBJ + J] = mm;
            ps[row * NBJ + J] = sv;
            if (diagB) diag[row] = dd;
        }
    }

    // Col epilogue: combine 8 waves' partials for this block's 256 columns.
    __syncthreads();
    {
        int j = threadIdx.x;
        if (j < 256) {
            float2 pp = colp[0][j];
            float M = pp.x, S = pp.y;
#pragma unroll
            for (int w = 1; w < 8; ++w) {
                float2 qq = colp[w][j];
                float mn = fmaxf(M, qq.x);
                S = S * __builtin_amdgcn_exp2f(M - mn) + qq.y * __builtin_amdgcn_exp2f(qq.x - mn);
                M = mn;
            }
            int col = J * 256 + j;
            cm[col * NBI + I] = M;
            cs[col * NBI + I] = S;
        }
    }

    // Fused merge: group j covers rows [256j, 256j+256). cnt[j] is bumped by
    // blocks with J==j (64) and blocks with I>>1==j (64); 128th arrival merges.
    __threadfence();
    if (threadIdx.x == 0) {
        int f = 0;
        int o1 = atomicAdd(&ctrl[J], 1);
        if (o1 == 127) f = J + 1;
        int g2 = I >> 1;
        int o2 = atomicAdd(&ctrl[g2], 1);
        if (o2 == 127) f |= (g2 + 1) << 8;
        mflag = f;
    }
    __syncthreads();
    const int fl = mflag;                      // block-uniform
#pragma unroll
    for (int pass = 0; pass < 2; ++pass) {
        int gj = (pass == 0 ? (fl & 255) : (fl >> 8)) - 1;
        if (gj < 0) continue;                  // uniform branch
        __threadfence();
        float v = 0.0f;
        if (threadIdx.x < 256) {
            int i = gj * 256 + threadIdx.x;
            const float* pmr = pm + i * NBJ;
            const float* psr = ps + i * NBJ;
            const float* cmr = cm + i * NBI;
            const float* csr = cs + i * NBI;
            float mt = -INFINITY, mc = -INFINITY;
#pragma unroll
            for (int pp = 0; pp < NBJ; ++pp) mt = fmaxf(mt, pmr[pp]);
#pragma unroll
            for (int pp = 0; pp < NBI; ++pp) mc = fmaxf(mc, cmr[pp]);
            float st = 0.0f, sc2 = 0.0f;
#pragma unroll
            for (int pp = 0; pp < NBJ; ++pp) st += psr[pp] * __builtin_amdgcn_exp2f(pmr[pp] - mt);
#pragma unroll
            for (int pp = 0; pp < NBI; ++pp) sc2 += csr[pp] * __builtin_amdgcn_exp2f(cmr[pp] - mc);
            v = 2.0f * diag[i] - mt - __builtin_amdgcn_logf(st)
                                - mc - __builtin_amdgcn_logf(sc2);
        }
#pragma unroll
        for (int off = 32; off; off >>= 1) v += __shfl_down(v, off, 64);
        if (lane == 0) wsum[wv] = v;
        __syncthreads();
        if (threadIdx.x == 0) {
            float bsum = 0.0f;
#pragma unroll
            for (int w = 0; w < 8; ++w) bsum += wsum[w];
            atomicAdd(acc, bsum);
            __threadfence();
            int old = atomicAdd(&ctrl[32], 1);
            if (old == 31) {                   // all 32 merge groups done
                __threadfence();
                float tot = atomicAdd(acc, 0.0f);
                float tt = -(tot * LN2F) / (2.0f * NROWS);
                if (!isfinite(tt)) tt = 0.0f;
                out[0] = tt;
            }
        }
        __syncthreads();                       // wsum reuse safety
    }
}

extern "C" void kernel_launch(void* const* d_in, const int* in_sizes, int n_in,
                              void* d_out, int out_size, void* d_ws, size_t ws_size,
                              hipStream_t stream) {
    const float* ts = (const float*)d_in[0];
    const float* nt = (const float*)d_in[1];
    float* out = (float*)d_out;

    unsigned short* ts_bf = (unsigned short*)d_ws;                 // 2 MB (fragment-major)
    unsigned short* nt_bf = ts_bf + NROWS * DDIM;                  // 2 MB (fragment-major)
    float* pm = (float*)(nt_bf + NROWS * DDIM);                    // 1 MB
    float* ps = pm + NROWS * NBJ;                                  // 1 MB
    float* cm = ps + NROWS * NBJ;                                  // 2 MB
    float* cs = cm + NROWS * NBI;                                  // 2 MB
    float* diag = cs + NROWS * NBI;                                // 32 KB
    float* acc = diag + NROWS;                                     // 4 B
    int* ctrl = (int*)(acc + 1);                                   // 33 ints

    convert_kernel<<<1024, 256, 0, stream>>>(ts, nt, ts_bf, nt_bf, acc, ctrl);
    tile_kernel<<<dim3(NBI, NBJ), 512, 0, stream>>>(
        ts_bf, nt_bf, pm, ps, cm, cs, diag, acc, ctrl, out);
}

// Round 12
// 401.071 us; speedup vs baseline: 1.4974x; 1.4974x over previous
//
#include <hip/hip_runtime.h>
#include <stdint.h>

#define NROWS 8192
#define DDIM  128
#define PPART 16
#define BROWS 256                        // rows per block = 8 waves * 32
#define NITER 8                          // 8 stages of 64 B-rows = 512-col partition
#define LOG2E_X100 144.26950408889634f   // 100 / ln(2)
#define LN2F       0.6931471805599453f

typedef __bf16 bf16x8 __attribute__((ext_vector_type(8)));
typedef float  f32x4  __attribute__((ext_vector_type(4)));
typedef unsigned short u16x8 __attribute__((ext_vector_type(8)));

// Fragment-major (F) layout: for strip g (16 rows), k-chunk kc (32 cols):
//   1 KB block at byte offset (g*4+kc)*1024; lane L=(quad*16+c) piece at L*16,
//   holding row (g*16+c), bytes [(kc*4+quad)*16 .. +16).
// DMA (global->LDS), ds_read, and A-frag loads all run at linear lane*16.

__device__ __forceinline__ unsigned short f2bf_rne(float f) {
    union { float f; uint32_t u; } v; v.f = f;
    uint32_t r = (v.u + 0x7FFFu + ((v.u >> 16) & 1u)) >> 16;
    return (unsigned short)r;
}

__device__ __forceinline__ void async16(const unsigned short* g, unsigned char* l) {
    __builtin_amdgcn_global_load_lds(
        (const __attribute__((address_space(1))) unsigned int*)g,
        (__attribute__((address_space(3))) unsigned int*)l, 16, 0, 0);
}

// Kernel 1: fp32 -> bf16 into FRAGMENT-MAJOR layout. ts pre-scaled by
// 100*log2(e) (base-2 softmax space). One thread = one 16B output chunk.
__global__ void convert_kernel(const float* __restrict__ ts, const float* __restrict__ nt,
                               unsigned short* __restrict__ ts_bf,
                               unsigned short* __restrict__ nt_bf,
                               float* __restrict__ acc, int* __restrict__ ticket) {
    const int nchunk = (NROWS * DDIM) / 8;          // 131072 chunks per matrix
    int tid = blockIdx.x * blockDim.x + threadIdx.x; // 0 .. 2*nchunk-1
    bool isNT = tid >= nchunk;
    int i = isNT ? (tid - nchunk) : tid;
    const float4* src = (const float4*)(isNT ? nt : ts) + i * 2;
    float4 v0 = src[0], v1 = src[1];
    float sc = isNT ? 1.0f : LOG2E_X100;
    u16x8 o;
    o[0] = f2bf_rne(v0.x * sc); o[1] = f2bf_rne(v0.y * sc);
    o[2] = f2bf_rne(v0.z * sc); o[3] = f2bf_rne(v0.w * sc);
    o[4] = f2bf_rne(v1.x * sc); o[5] = f2bf_rne(v1.y * sc);
    o[6] = f2bf_rne(v1.z * sc); o[7] = f2bf_rne(v1.w * sc);
    int row = i >> 4, chunk = i & 15;               // row 0..8191, 16B-chunk 0..15
    int g = row >> 4, c = row & 15;
    int kc = chunk >> 2, quad = chunk & 3;
    int off16 = (g * 4 + kc) * 64 + quad * 16 + c;  // in 16B units
    ((u16x8*)(isNT ? nt_bf : ts_bf))[off16] = o;
    if (tid == 0) { *acc = 0.0f; *ticket = 0; }
}

// DMA one 64-row stage (16 KB, contiguous in F layout) into LDS, split across
// 8 waves (2 x 1KB instructions each). Fully coalesced; LDS lands operand-ordered.
__device__ __forceinline__ void dma_stage(const unsigned short* g, unsigned char* l,
                                          int lane, int wv) {
#pragma unroll
    for (int k = 0; k < 2; ++k) {
        int u = wv * 2 + k;                        // block 0..15 of the stage
        async16(g + u * 512 + lane * 8, l + u * 1024);
    }
}

// Kernel 2: per-row online-softmax stats, base-2 space. 8 waves/block; each
// wave = 32 rows (2 strips). 64 B-rows/stage double-buffered in LDS
// (fragment-major: conflict-free lane-linear ds_read_b128, imm offsets).
// grid = (NROWS/BROWS, PPART, 2) = 1024 blocks -> 4 blocks/CU co-resident.
__global__ __launch_bounds__(512, 4) void rowstats_kernel(
        const unsigned short* __restrict__ ts_bf,
        const unsigned short* __restrict__ nt_bf,
        float* __restrict__ pm, float* __restrict__ ps, float* __restrict__ pd) {
    __shared__ unsigned char smem[2 * 16384];

    const int lane = threadIdx.x & 63;
    const int wv   = threadIdx.x >> 6;         // 0..7
    const int c    = lane & 15;
    const int quad = lane >> 4;
    const int bx   = blockIdx.x;               // 0..31
    const int part = blockIdx.y;               // 0..15
    const int dir  = blockIdx.z;
    const int rows0 = bx * BROWS + wv * 32;

    const unsigned short* A = dir ? nt_bf : ts_bf;   // fragment-major
    const unsigned short* B = dir ? ts_bf : nt_bf;   // fragment-major

    // A fragments: this wave's strips G0, G0+1; lane-linear coalesced loads.
    const int G0 = bx * 16 + wv * 2;
    bf16x8 a[2][4];
#pragma unroll
    for (int s = 0; s < 2; ++s)
#pragma unroll
        for (int kc = 0; kc < 4; ++kc)
            a[s][kc] = *(const bf16x8*)(A + ((G0 + s) * 4 + kc) * 512 + lane * 8);

    float m[2][4], ss[2][4], dg[2][4];
#pragma unroll
    for (int s = 0; s < 2; ++s)
#pragma unroll
        for (int r = 0; r < 4; ++r) { m[s][r] = -INFINITY; ss[s][r] = 0.0f; dg[s][r] = 0.0f; }

    // Diagonal bookkeeping (PPART=16: partition = 32 col-tiles, 4 tiles/stage).
    // Wave strips G0=bx*16+2wv (+s): partition bx>>1, local tile (bx&1)*16+2wv+s
    // -> stage t_d = (bx&1)*4 + (wv>>1), slots l0 = (wv&1)*2 (+s).
    const bool havePart = (part == (bx >> 1));
    const int  t_d = (bx & 1) * 4 + (wv >> 1);
    const int  l0  = (wv & 1) * 2;

    // Partition B base: strip part*32 (32 strips = 512 cols per partition).
    const unsigned short* bwalk = B + part * 32 * 2048;

    dma_stage(bwalk, smem, lane, wv);
    __syncthreads();

    for (int t = 0; t < NITER; ++t) {
        if (t + 1 < NITER)
            dma_stage(bwalk + (t + 1) * 8192, smem + ((t + 1) & 1) * 16384, lane, wv);

        const unsigned char* buf = smem + (t & 1) * 16384 + lane * 16;

        f32x4 av[4][2];
#pragma unroll
        for (int l = 0; l < 4; ++l)
#pragma unroll
            for (int s = 0; s < 2; ++s) av[l][s] = (f32x4){0.f, 0.f, 0.f, 0.f};

#pragma unroll
        for (int kc = 0; kc < 4; ++kc) {
            bf16x8 b0 = *(const bf16x8*)(buf + kc * 1024);
            bf16x8 b1 = *(const bf16x8*)(buf + kc * 1024 + 4096);
            bf16x8 b2 = *(const bf16x8*)(buf + kc * 1024 + 8192);
            bf16x8 b3 = *(const bf16x8*)(buf + kc * 1024 + 12288);
            av[0][0] = __builtin_amdgcn_mfma_f32_16x16x32_bf16(a[0][kc], b0, av[0][0], 0, 0, 0);
            av[0][1] = __builtin_amdgcn_mfma_f32_16x16x32_bf16(a[1][kc], b0, av[0][1], 0, 0, 0);
            av[1][0] = __builtin_amdgcn_mfma_f32_16x16x32_bf16(a[0][kc], b1, av[1][0], 0, 0, 0);
            av[1][1] = __builtin_amdgcn_mfma_f32_16x16x32_bf16(a[1][kc], b1, av[1][1], 0, 0, 0);
            av[2][0] = __builtin_amdgcn_mfma_f32_16x16x32_bf16(a[0][kc], b2, av[2][0], 0, 0, 0);
            av[2][1] = __builtin_amdgcn_mfma_f32_16x16x32_bf16(a[1][kc], b2, av[2][1], 0, 0, 0);
            av[3][0] = __builtin_amdgcn_mfma_f32_16x16x32_bf16(a[0][kc], b3, av[3][0], 0, 0, 0);
            av[3][1] = __builtin_amdgcn_mfma_f32_16x16x32_bf16(a[1][kc], b3, av[3][1], 0, 0, 0);
        }

        const bool pd_ = havePart && (t == t_d);   // wave-uniform, true for 1 stage
#pragma unroll
        for (int s = 0; s < 2; ++s) {
#pragma unroll
            for (int r = 0; r < 4; ++r) {
                float x0 = av[0][s][r], x1 = av[1][s][r];
                float x2 = av[2][s][r], x3 = av[3][s][r];
                if (pd_) {
                    const int dslot = l0 + s;       // wave-uniform 0..3
                    bool onDiag = (c == quad * 4 + r);
                    float xv = dslot == 0 ? x0 : dslot == 1 ? x1 : dslot == 2 ? x2 : x3;
                    if (onDiag) dg[s][r] += xv;
                    float rep = onDiag ? xv : -1.0e30f;
                    if (dslot == 0) x0 = rep; else if (dslot == 1) x1 = rep;
                    else if (dslot == 2) x2 = rep; else x3 = rep;
                }
                float mn = fmaxf(fmaxf(fmaxf(x0, x1), fmaxf(x2, x3)), m[s][r]);
                float e  = __builtin_amdgcn_exp2f(m[s][r] - mn);
                float es = (__builtin_amdgcn_exp2f(x0 - mn) + __builtin_amdgcn_exp2f(x1 - mn))
                         + (__builtin_amdgcn_exp2f(x2 - mn) + __builtin_amdgcn_exp2f(x3 - mn));
                ss[s][r] = fmaf(ss[s][r], e, es);
                m[s][r] = mn;
            }
        }
        __syncthreads();
    }

    // Epilogue: 16-lane combine per quad. Max-reduce, single rescale, sum-reduce.
#pragma unroll
    for (int s = 0; s < 2; ++s) {
#pragma unroll
        for (int r = 0; r < 4; ++r) {
            float mm = m[s][r];
#pragma unroll
            for (int off = 1; off < 16; off <<= 1)
                mm = fmaxf(mm, __shfl_xor(mm, off, 64));
            float sv = ss[s][r] * __builtin_amdgcn_exp2f(m[s][r] - mm);
            float dd = dg[s][r];
#pragma unroll
            for (int off = 1; off < 16; off <<= 1) {
                sv += __shfl_xor(sv, off, 64);
                dd += __shfl_xor(dd, off, 64);
            }
            if (c == 0) {
                int row = rows0 + s * 16 + quad * 4 + r;
                int idx = (dir * NROWS + row) * PPART + part;
                pm[idx] = mm; ps[idx] = sv; pd[idx] = dd;
            }
        }
    }
}

// Kernel 3: merge partitions per (dir,row), block-reduce, atomicAdd;
// last block finalizes the scalar output (base-2 -> natural via ln2).
__global__ void merge_kernel(const float* __restrict__ pm, const float* __restrict__ ps,
                             const float* __restrict__ pd, float* __restrict__ acc,
                             int* __restrict__ ticket, float* __restrict__ out) {
    int tid = blockIdx.x * blockDim.x + threadIdx.x;  // 0 .. 2*NROWS-1
    const float* pmr = pm + tid * PPART;
    const float* psr = ps + tid * PPART;
    const float* pdr = pd + tid * PPART;
    float mt = -INFINITY;
#pragma unroll
    for (int p = 0; p < PPART; ++p) mt = fmaxf(mt, pmr[p]);
    float st = 0.0f, dt = 0.0f;
#pragma unroll
    for (int p = 0; p < PPART; ++p) {
        st += psr[p] * __builtin_amdgcn_exp2f(pmr[p] - mt);
        dt += pdr[p];
    }
    float lsm = dt - mt - __builtin_amdgcn_logf(st);   // base-2 log-softmax at diagonal

    float v = lsm;
#pragma unroll
    for (int off = 32; off; off >>= 1) v += __shfl_down(v, off, 64);
    __shared__ float wsum[4];
    if ((threadIdx.x & 63) == 0) wsum[threadIdx.x >> 6] = v;
    __syncthreads();
    if (threadIdx.x == 0) {
        atomicAdd(acc, wsum[0] + wsum[1] + wsum[2] + wsum[3]);
        __threadfence();
        int old = atomicAdd(ticket, 1);
        if (old == (int)gridDim.x - 1) {
            __threadfence();
            float tot = atomicAdd(acc, 0.0f);   // coherent read of final sum
            float t = -(tot * LN2F) / (2.0f * NROWS);
            if (!isfinite(t)) t = 0.0f;
            out[0] = t;
        }
    }
}

extern "C" void kernel_launch(void* const* d_in, const int* in_sizes, int n_in,
                              void* d_out, int out_size, void* d_ws, size_t ws_size,
                              hipStream_t stream) {
    const float* ts = (const float*)d_in[0];
    const float* nt = (const float*)d_in[1];
    float* out = (float*)d_out;

    unsigned short* ts_bf = (unsigned short*)d_ws;                 // 2 MB (fragment-major)
    unsigned short* nt_bf = ts_bf + NROWS * DDIM;                  // 2 MB (fragment-major)
    float* pm = (float*)(nt_bf + NROWS * DDIM);                    // 1 MB
    float* ps = pm + 2 * NROWS * PPART;                            // 1 MB
    float* pd = ps + 2 * NROWS * PPART;                            // 1 MB
    float* acc = pd + 2 * NROWS * PPART;                           // 4 B
    int* ticket = (int*)(acc + 1);                                 // 4 B

    convert_kernel<<<1024, 256, 0, stream>>>(ts, nt, ts_bf, nt_bf, acc, ticket);
    rowstats_kernel<<<dim3(NROWS / BROWS, PPART, 2), 512, 0, stream>>>(ts_bf, nt_bf, pm, ps, pd);
    merge_kernel<<<(2 * NROWS) / 256, 256, 0, stream>>>(pm, ps, pd, acc, ticket, out);
}

// Round 13
// 136.705 us; speedup vs baseline: 4.3931x; 2.9338x over previous
//
#include <hip/hip_runtime.h>
#include <stdint.h>

#define NROWS 8192
#define DDIM  128
#define PPART 16
#define BROWS 256                        // rows per block = 8 waves * 32
#define NITER 8                          // 8 stages of 64 B-rows = 512-col partition
#define LOG2E_X100 144.26950408889634f   // 100 / ln(2)
#define LN2F       0.6931471805599453f

typedef __bf16 bf16x8 __attribute__((ext_vector_type(8)));
typedef float  f32x4  __attribute__((ext_vector_type(4)));
typedef unsigned short u16x8 __attribute__((ext_vector_type(8)));

// Fragment-major (F) layout: for strip g (16 rows), k-chunk kc (32 cols):
//   1 KB block at byte offset (g*4+kc)*1024; lane L=(quad*16+c) piece at L*16,
//   holding row (g*16+c), bytes [(kc*4+quad)*16 .. +16).
// DMA (global->LDS), ds_read, and A-frag loads all run at linear lane*16.

__device__ __forceinline__ unsigned short f2bf_rne(float f) {
    union { float f; uint32_t u; } v; v.f = f;
    uint32_t r = (v.u + 0x7FFFu + ((v.u >> 16) & 1u)) >> 16;
    return (unsigned short)r;
}

__device__ __forceinline__ void async16(const unsigned short* g, unsigned char* l) {
    __builtin_amdgcn_global_load_lds(
        (const __attribute__((address_space(1))) unsigned int*)g,
        (__attribute__((address_space(3))) unsigned int*)l, 16, 0, 0);
}

// Kernel 1: fp32 -> bf16 into FRAGMENT-MAJOR layout. ts pre-scaled by
// 100*log2(e) (base-2 softmax space). One thread = one 16B output chunk.
__global__ void convert_kernel(const float* __restrict__ ts, const float* __restrict__ nt,
                               unsigned short* __restrict__ ts_bf,
                               unsigned short* __restrict__ nt_bf,
                               float* __restrict__ acc, int* __restrict__ ticket) {
    const int nchunk = (NROWS * DDIM) / 8;          // 131072 chunks per matrix
    int tid = blockIdx.x * blockDim.x + threadIdx.x; // 0 .. 2*nchunk-1
    bool isNT = tid >= nchunk;
    int i = isNT ? (tid - nchunk) : tid;
    const float4* src = (const float4*)(isNT ? nt : ts) + i * 2;
    float4 v0 = src[0], v1 = src[1];
    float sc = isNT ? 1.0f : LOG2E_X100;
    u16x8 o;
    o[0] = f2bf_rne(v0.x * sc); o[1] = f2bf_rne(v0.y * sc);
    o[2] = f2bf_rne(v0.z * sc); o[3] = f2bf_rne(v0.w * sc);
    o[4] = f2bf_rne(v1.x * sc); o[5] = f2bf_rne(v1.y * sc);
    o[6] = f2bf_rne(v1.z * sc); o[7] = f2bf_rne(v1.w * sc);
    int row = i >> 4, chunk = i & 15;               // row 0..8191, 16B-chunk 0..15
    int g = row >> 4, c = row & 15;
    int kc = chunk >> 2, quad = chunk & 3;
    int off16 = (g * 4 + kc) * 64 + quad * 16 + c;  // in 16B units
    ((u16x8*)(isNT ? nt_bf : ts_bf))[off16] = o;
    if (tid == 0) { *acc = 0.0f; *ticket = 0; }
}

// DMA one 64-row stage (16 KB, contiguous in F layout) into LDS, split across
// 8 waves (2 x 1KB instructions each). Fully coalesced; LDS lands operand-ordered.
__device__ __forceinline__ void dma_stage(const unsigned short* g, unsigned char* l,
                                          int lane, int wv) {
#pragma unroll
    for (int k = 0; k < 2; ++k) {
        int u = wv * 2 + k;                        // block 0..15 of the stage
        async16(g + u * 512 + lane * 8, l + u * 1024);
    }
}

// Kernel 2: per-row online-softmax stats, base-2 space. 8 waves/block; each
// wave = 32 rows (2 strips). 64 B-rows/stage double-buffered in LDS
// (fragment-major: conflict-free lane-linear ds_read_b128, imm offsets).
// Slots processed in PAIRS to halve accumulator live-set (spill-proof: peak
// ~95 regs under the (512,4)=128 budget). grid = (32, 16, 2) -> 4 blocks/CU.
__global__ __launch_bounds__(512, 4) void rowstats_kernel(
        const unsigned short* __restrict__ ts_bf,
        const unsigned short* __restrict__ nt_bf,
        float* __restrict__ pm, float* __restrict__ ps, float* __restrict__ pd) {
    __shared__ unsigned char smem[2 * 16384];

    const int lane = threadIdx.x & 63;
    const int wv   = threadIdx.x >> 6;         // 0..7
    const int c    = lane & 15;
    const int quad = lane >> 4;
    const int bx   = blockIdx.x;               // 0..31
    const int part = blockIdx.y;               // 0..15
    const int dir  = blockIdx.z;
    const int rows0 = bx * BROWS + wv * 32;

    const unsigned short* A = dir ? nt_bf : ts_bf;   // fragment-major
    const unsigned short* B = dir ? ts_bf : nt_bf;   // fragment-major

    // A fragments: this wave's strips G0, G0+1; lane-linear coalesced loads.
    const int G0 = bx * 16 + wv * 2;
    bf16x8 a[2][4];
#pragma unroll
    for (int s = 0; s < 2; ++s)
#pragma unroll
        for (int kc = 0; kc < 4; ++kc)
            a[s][kc] = *(const bf16x8*)(A + ((G0 + s) * 4 + kc) * 512 + lane * 8);

    float m[2][4], ss[2][4], dg[2][4];
#pragma unroll
    for (int s = 0; s < 2; ++s)
#pragma unroll
        for (int r = 0; r < 4; ++r) { m[s][r] = -INFINITY; ss[s][r] = 0.0f; dg[s][r] = 0.0f; }

    // Diagonal bookkeeping (PPART=16: partition = 32 col-tiles, 4 tiles/stage).
    // Wave strips G0=bx*16+2wv (+s): partition bx>>1, local tile (bx&1)*16+2wv+s
    // -> stage t_d = (bx&1)*4 + (wv>>1), pair p_d = wv&1, within-pair slot = s.
    const bool havePart = (part == (bx >> 1));
    const int  t_d = (bx & 1) * 4 + (wv >> 1);
    const int  p_d = wv & 1;

    // Partition B base: strip part*32 (32 strips = 512 cols per partition).
    const unsigned short* bwalk = B + part * 32 * 2048;

    dma_stage(bwalk, smem, lane, wv);
    __syncthreads();

    for (int t = 0; t < NITER; ++t) {
        if (t + 1 < NITER)
            dma_stage(bwalk + (t + 1) * 8192, smem + ((t + 1) & 1) * 16384, lane, wv);

        const unsigned char* buf = smem + (t & 1) * 16384 + lane * 16;
        const bool pd_ = havePart && (t == t_d);   // wave-uniform, true for 1 stage

#pragma unroll
        for (int p = 0; p < 2; ++p) {              // slot pair {2p, 2p+1}
            f32x4 av00 = {0.f,0.f,0.f,0.f}, av01 = {0.f,0.f,0.f,0.f};
            f32x4 av10 = {0.f,0.f,0.f,0.f}, av11 = {0.f,0.f,0.f,0.f};
#pragma unroll
            for (int kc = 0; kc < 4; ++kc) {
                bf16x8 b0 = *(const bf16x8*)(buf + kc * 1024 + (2 * p)     * 4096);
                bf16x8 b1 = *(const bf16x8*)(buf + kc * 1024 + (2 * p + 1) * 4096);
                av00 = __builtin_amdgcn_mfma_f32_16x16x32_bf16(a[0][kc], b0, av00, 0, 0, 0);
                av01 = __builtin_amdgcn_mfma_f32_16x16x32_bf16(a[1][kc], b0, av01, 0, 0, 0);
                av10 = __builtin_amdgcn_mfma_f32_16x16x32_bf16(a[0][kc], b1, av10, 0, 0, 0);
                av11 = __builtin_amdgcn_mfma_f32_16x16x32_bf16(a[1][kc], b1, av11, 0, 0, 0);
            }

            const bool pdp = pd_ && (p == p_d);    // wave-uniform
#pragma unroll
            for (int s = 0; s < 2; ++s) {
#pragma unroll
                for (int r = 0; r < 4; ++r) {
                    float x0 = s ? av01[r] : av00[r];   // slot 2p
                    float x1 = s ? av11[r] : av10[r];   // slot 2p+1
                    if (pdp) {
                        // strip s's diag tile is within-pair slot s
                        bool onDiag = (c == quad * 4 + r);
                        float xv = s ? x1 : x0;
                        if (onDiag) dg[s][r] += xv;
                        float rep = onDiag ? xv : -1.0e30f;
                        if (s) x1 = rep; else x0 = rep;
                    }
                    float mn = fmaxf(fmaxf(x0, x1), m[s][r]);   // v_max3
                    float e  = __builtin_amdgcn_exp2f(m[s][r] - mn);
                    ss[s][r] = fmaf(ss[s][r], e, __builtin_amdgcn_exp2f(x0 - mn)
                                               + __builtin_amdgcn_exp2f(x1 - mn));
                    m[s][r] = mn;
                }
            }
        }
        __syncthreads();
    }

    // Epilogue: 16-lane combine per quad. Max-reduce, single rescale, sum-reduce.
#pragma unroll
    for (int s = 0; s < 2; ++s) {
#pragma unroll
        for (int r = 0; r < 4; ++r) {
            float mm = m[s][r];
#pragma unroll
            for (int off = 1; off < 16; off <<= 1)
                mm = fmaxf(mm, __shfl_xor(mm, off, 64));
            float sv = ss[s][r] * __builtin_amdgcn_exp2f(m[s][r] - mm);
            float dd = dg[s][r];
#pragma unroll
            for (int off = 1; off < 16; off <<= 1) {
                sv += __shfl_xor(sv, off, 64);
                dd += __shfl_xor(dd, off, 64);
            }
            if (c == 0) {
                int row = rows0 + s * 16 + quad * 4 + r;
                int idx = (dir * NROWS + row) * PPART + part;
                pm[idx] = mm; ps[idx] = sv; pd[idx] = dd;
            }
        }
    }
}

// Kernel 3: merge partitions per (dir,row), block-reduce, atomicAdd;
// last block finalizes the scalar output (base-2 -> natural via ln2).
__global__ void merge_kernel(const float* __restrict__ pm, const float* __restrict__ ps,
                             const float* __restrict__ pd, float* __restrict__ acc,
                             int* __restrict__ ticket, float* __restrict__ out) {
    int tid = blockIdx.x * blockDim.x + threadIdx.x;  // 0 .. 2*NROWS-1
    const float* pmr = pm + tid * PPART;
    const float* psr = ps + tid * PPART;
    const float* pdr = pd + tid * PPART;
    float mt = -INFINITY;
#pragma unroll
    for (int p = 0; p < PPART; ++p) mt = fmaxf(mt, pmr[p]);
    float st = 0.0f, dt = 0.0f;
#pragma unroll
    for (int p = 0; p < PPART; ++p) {
        st += psr[p] * __builtin_amdgcn_exp2f(pmr[p] - mt);
        dt += pdr[p];
    }
    float lsm = dt - mt - __builtin_amdgcn_logf(st);   // base-2 log-softmax at diagonal

    float v = lsm;
#pragma unroll
    for (int off = 32; off; off >>= 1) v += __shfl_down(v, off, 64);
    __shared__ float wsum[4];
    if ((threadIdx.x & 63) == 0) wsum[threadIdx.x >> 6] = v;
    __syncthreads();
    if (threadIdx.x == 0) {
        atomicAdd(acc, wsum[0] + wsum[1] + wsum[2] + wsum[3]);
        __threadfence();
        int old = atomicAdd(ticket, 1);
        if (old == (int)gridDim.x - 1) {
            __threadfence();
            float tot = atomicAdd(acc, 0.0f);   // coherent read of final sum
            float t = -(tot * LN2F) / (2.0f * NROWS);
            if (!isfinite(t)) t = 0.0f;
            out[0] = t;
        }
    }
}

extern "C" void kernel_launch(void* const* d_in, const int* in_sizes, int n_in,
                              void* d_out, int out_size, void* d_ws, size_t ws_size,
                              hipStream_t stream) {
    const float* ts = (const float*)d_in[0];
    const float* nt = (const float*)d_in[1];
    float* out = (float*)d_out;

    unsigned short* ts_bf = (unsigned short*)d_ws;                 // 2 MB (fragment-major)
    unsigned short* nt_bf = ts_bf + NROWS * DDIM;                  // 2 MB (fragment-major)
    float* pm = (float*)(nt_bf + NROWS * DDIM);                    // 1 MB
    float* ps = pm + 2 * NROWS * PPART;                            // 1 MB
    float* pd = ps + 2 * NROWS * PPART;                            // 1 MB
    float* acc = pd + 2 * NROWS * PPART;                           // 4 B
    int* ticket = (int*)(acc + 1);                                 // 4 B

    convert_kernel<<<1024, 256, 0, stream>>>(ts, nt, ts_bf, nt_bf, acc, ticket);
    rowstats_kernel<<<dim3(NROWS / BROWS, PPART, 2), 512, 0, stream>>>(ts_bf, nt_bf, pm, ps, pd);
    merge_kernel<<<(2 * NROWS) / 256, 256, 0, stream>>>(pm, ps, pd, acc, ticket, out);
}